// Round 1
// baseline (324.385 us; speedup 1.0000x reference)
//
#include <hip/hip_runtime.h>

// Problem constants
#define D_MODEL 1024
#define NHEAD   16
#define DK      64
#define BATCH   2
#define SEQ     2048
#define M_TOT   (BATCH*SEQ)   // 4096

typedef unsigned short u16;
typedef __attribute__((ext_vector_type(8))) __bf16 bf16x8;
typedef __attribute__((ext_vector_type(8))) u16   u16x8;
typedef __attribute__((ext_vector_type(4))) float f32x4;

__device__ __forceinline__ u16 f2bf(float f) {
  union { float f; unsigned u; } v; v.f = f;
  return (u16)((v.u + 0x7fffu + ((v.u >> 16) & 1u)) >> 16);
}

// ---------------- fp32 -> bf16 convert, 8 elems/thread ----------------
__global__ void cvt_kernel(const float* __restrict__ src, u16* __restrict__ dst, int n8) {
  int i = blockIdx.x * blockDim.x + threadIdx.x;
  if (i >= n8) return;
  const float4* s = (const float4*)src + (size_t)i * 2;
  float4 a = s[0], b = s[1];
  u16x8 o;
  o[0]=f2bf(a.x); o[1]=f2bf(a.y); o[2]=f2bf(a.z); o[3]=f2bf(a.w);
  o[4]=f2bf(b.x); o[5]=f2bf(b.y); o[6]=f2bf(b.z); o[7]=f2bf(b.w);
  *((u16x8*)dst + i) = o;
}

// ---------------- shared GEMM mainloop ----------------
// C[m,n] = sum_k A[m,k]*B[n,k]   (both A and B row-major with K=1024 contiguous, bf16)
// Tile: BM=128, BN=128, BK=32. 256 threads = 4 waves (2x2), each wave 64x64 = 4x4 frags.
#define BM 128
#define BN 128
#define BK 32
#define LDP 40   // padded LDS row length (elements); 80B stride -> 2-way bank alias (free)

__device__ __forceinline__ void gemm_mainloop(
    const u16* __restrict__ A, const u16* __restrict__ Bm,
    int mbase, int nbase, u16* la, u16* lb, f32x4 acc[4][4])
{
  const int tid  = threadIdx.x;
  const int lane = tid & 63;
  const int wid  = tid >> 6;
  const int wr   = (wid >> 1) * 64, wc = (wid & 1) * 64;
  const int lr   = lane & 15, lg = lane >> 4;
  // staging: 512 16B-units per tile; thread t handles units t and t+256 of A and B
  const int r0 = tid >> 2;            // row 0..63
  const int s0 = (tid & 3) * 8;       // elem offset within row
  for (int k0 = 0; k0 < 1024; k0 += BK) {
    uint4 a0 = *(const uint4*)&A [(size_t)(mbase + r0)      * 1024 + k0 + s0];
    uint4 a1 = *(const uint4*)&A [(size_t)(mbase + r0 + 64) * 1024 + k0 + s0];
    uint4 b0 = *(const uint4*)&Bm[(size_t)(nbase + r0)      * 1024 + k0 + s0];
    uint4 b1 = *(const uint4*)&Bm[(size_t)(nbase + r0 + 64) * 1024 + k0 + s0];
    __syncthreads();
    *(uint4*)&la[(r0)      * LDP + s0] = a0;
    *(uint4*)&la[(r0 + 64) * LDP + s0] = a1;
    *(uint4*)&lb[(r0)      * LDP + s0] = b0;
    *(uint4*)&lb[(r0 + 64) * LDP + s0] = b1;
    __syncthreads();
    bf16x8 af[4], bfr[4];
    #pragma unroll
    for (int i = 0; i < 4; ++i)
      af[i] = *(const bf16x8*)&la[(wr + i*16 + lr) * LDP + lg * 8];
    #pragma unroll
    for (int j = 0; j < 4; ++j)
      bfr[j] = *(const bf16x8*)&lb[(wc + j*16 + lr) * LDP + lg * 8];
    #pragma unroll
    for (int i = 0; i < 4; ++i)
      #pragma unroll
      for (int j = 0; j < 4; ++j)
        acc[i][j] = __builtin_amdgcn_mfma_f32_16x16x32_bf16(af[i], bfr[j], acc[i][j], 0, 0, 0);
  }
}

// ---------------- fused QKV projection ----------------
// z=0: Q (scaled by 1/8) -> qws [b,h,s,dk] ; z=1: K -> kws [b,h,s,dk] ; z=2: V -> vtws [b,h,dk,s]
__global__ __launch_bounds__(256) void qkv_gemm(
    const u16* __restrict__ xbf, const u16* __restrict__ wbf,
    const float* __restrict__ bq, const float* __restrict__ bk, const float* __restrict__ bv,
    u16* __restrict__ qws, u16* __restrict__ kws, u16* __restrict__ vtws)
{
  __shared__ u16 lds[2 * BM * LDP];
  const int z     = blockIdx.z;
  const int nbase = blockIdx.x * BN;
  const int mbase = blockIdx.y * BM;
  const u16*  Bw   = wbf + (size_t)z * 1024 * 1024;
  const float* bias = (z == 0) ? bq : (z == 1) ? bk : bv;
  f32x4 acc[4][4];
  #pragma unroll
  for (int i = 0; i < 4; ++i)
    #pragma unroll
    for (int j = 0; j < 4; ++j)
      acc[i][j] = (f32x4){0.f, 0.f, 0.f, 0.f};
  gemm_mainloop(xbf, Bw, mbase, nbase, lds, lds + BM * LDP, acc);

  const int lane = threadIdx.x & 63;
  const int wid  = threadIdx.x >> 6;
  const int wr   = (wid >> 1) * 64, wc = (wid & 1) * 64;
  const int lr   = lane & 15, lg = lane >> 4;
  #pragma unroll
  for (int i = 0; i < 4; ++i) {
    #pragma unroll
    for (int j = 0; j < 4; ++j) {
      int gn = nbase + wc + j*16 + lr;
      float bs = bias[gn];
      int h = gn >> 6, d = gn & 63;
      #pragma unroll
      for (int r = 0; r < 4; ++r) {
        int gm = mbase + wr + i*16 + lg*4 + r;
        int bb = gm >> 11, s = gm & 2047;
        float v = acc[i][j][r] + bs;
        if (z == 0)      qws [(((size_t)(bb*NHEAD + h)) * SEQ + s) * DK + d] = f2bf(v * 0.125f);
        else if (z == 1) kws [(((size_t)(bb*NHEAD + h)) * SEQ + s) * DK + d] = f2bf(v);
        else             vtws[(((size_t)(bb*NHEAD + h)) * DK  + d) * SEQ + s] = f2bf(v);
      }
    }
  }
}

// ---------------- output projection ----------------
__global__ __launch_bounds__(256) void out_gemm(
    const u16* __restrict__ ows, const u16* __restrict__ wobf,
    const float* __restrict__ bo, float* __restrict__ out)
{
  __shared__ u16 lds[2 * BM * LDP];
  const int nbase = blockIdx.x * BN;
  const int mbase = blockIdx.y * BM;
  f32x4 acc[4][4];
  #pragma unroll
  for (int i = 0; i < 4; ++i)
    #pragma unroll
    for (int j = 0; j < 4; ++j)
      acc[i][j] = (f32x4){0.f, 0.f, 0.f, 0.f};
  gemm_mainloop(ows, wobf, mbase, nbase, lds, lds + BM * LDP, acc);

  const int lane = threadIdx.x & 63;
  const int wid  = threadIdx.x >> 6;
  const int wr   = (wid >> 1) * 64, wc = (wid & 1) * 64;
  const int lr   = lane & 15, lg = lane >> 4;
  #pragma unroll
  for (int i = 0; i < 4; ++i) {
    #pragma unroll
    for (int j = 0; j < 4; ++j) {
      int gn = nbase + wc + j*16 + lr;
      float bs = bo[gn];
      #pragma unroll
      for (int r = 0; r < 4; ++r) {
        int gm = mbase + wr + i*16 + lg*4 + r;
        out[(size_t)gm * 1024 + gn] = acc[i][j][r] + bs;
      }
    }
  }
}

// ---------------- flash-style causal attention ----------------
// grid (32, 16, 2): qtile (reversed for heavy-first dispatch), head, batch.
// 4 waves/block, each wave owns 16 q-rows; KV tiles of 64.
__global__ __launch_bounds__(256) void attn_kernel(
    const u16* __restrict__ qws, const u16* __restrict__ kws,
    const u16* __restrict__ vtws, u16* __restrict__ ows)
{
  __shared__ u16 plds[4 * 16 * 72];   // per-wave 16x64 P tile, padded to 72
  const int qt = 31 - blockIdx.x;
  const int h  = blockIdx.y, b = blockIdx.z;
  const int bh = b * NHEAD + h;
  const int tid = threadIdx.x, wid = tid >> 6, lane = tid & 63;
  const int lr = lane & 15, lg = lane >> 4;
  const u16* Q  = qws  + (size_t)bh * SEQ * DK;
  const u16* K  = kws  + (size_t)bh * SEQ * DK;
  const u16* Vt = vtws + (size_t)bh * DK * SEQ;
  u16* myp = plds + wid * 16 * 72;
  const int qbase = qt * 64 + wid * 16;

  bf16x8 qf0 = *(const bf16x8*)&Q[(size_t)(qbase + lr) * DK + lg * 8];
  bf16x8 qf1 = *(const bf16x8*)&Q[(size_t)(qbase + lr) * DK + 32 + lg * 8];

  f32x4 oacc[4];
  float mrow[4], lrow[4];
  #pragma unroll
  for (int t = 0; t < 4; ++t) oacc[t] = (f32x4){0.f, 0.f, 0.f, 0.f};
  #pragma unroll
  for (int r = 0; r < 4; ++r) { mrow[r] = -1e30f; lrow[r] = 0.f; }

  const int ntiles = qt + 1;
  for (int kvt = 0; kvt < ntiles; ++kvt) {
    const int kvbase = kvt * 64;
    // ---- S = Q K^T (Q pre-scaled by 1/8) ----
    f32x4 sacc[4];
    #pragma unroll
    for (int t = 0; t < 4; ++t) {
      sacc[t] = (f32x4){0.f, 0.f, 0.f, 0.f};
      bf16x8 kf0 = *(const bf16x8*)&K[(size_t)(kvbase + t*16 + lr) * DK + lg * 8];
      bf16x8 kf1 = *(const bf16x8*)&K[(size_t)(kvbase + t*16 + lr) * DK + 32 + lg * 8];
      sacc[t] = __builtin_amdgcn_mfma_f32_16x16x32_bf16(qf0, kf0, sacc[t], 0, 0, 0);
      sacc[t] = __builtin_amdgcn_mfma_f32_16x16x32_bf16(qf1, kf1, sacc[t], 0, 0, 0);
    }
    // ---- causal mask ----
    #pragma unroll
    for (int t = 0; t < 4; ++t) {
      int kv = kvbase + t*16 + lr;
      #pragma unroll
      for (int r = 0; r < 4; ++r) {
        int q = qbase + lg*4 + r;
        if (kv > q) sacc[t][r] = -1e30f;
      }
    }
    // ---- online softmax (row stats; 16-lane groups hold full rows) ----
    #pragma unroll
    for (int r = 0; r < 4; ++r) {
      float mx = fmaxf(fmaxf(sacc[0][r], sacc[1][r]), fmaxf(sacc[2][r], sacc[3][r]));
      #pragma unroll
      for (int off = 1; off < 16; off <<= 1) mx = fmaxf(mx, __shfl_xor(mx, off));
      float mnew = fmaxf(mrow[r], mx);
      float alpha = __expf(mrow[r] - mnew);
      mrow[r] = mnew;
      float ps = 0.f;
      #pragma unroll
      for (int t = 0; t < 4; ++t) {
        float p = __expf(sacc[t][r] - mnew);
        sacc[t][r] = p;
        ps += p;
      }
      #pragma unroll
      for (int off = 1; off < 16; off <<= 1) ps += __shfl_xor(ps, off);
      lrow[r] = lrow[r] * alpha + ps;
      #pragma unroll
      for (int t = 0; t < 4; ++t) oacc[t][r] *= alpha;
    }
    // ---- P -> bf16 -> LDS (C-layout scatter), then re-read as A-frags ----
    #pragma unroll
    for (int t = 0; t < 4; ++t)
      #pragma unroll
      for (int r = 0; r < 4; ++r)
        myp[(lg*4 + r) * 72 + t*16 + lr] = f2bf(sacc[t][r]);
    bf16x8 pf0 = *(const bf16x8*)&myp[lr * 72 + lg * 8];
    bf16x8 pf1 = *(const bf16x8*)&myp[lr * 72 + 32 + lg * 8];
    // ---- O += P V ----
    #pragma unroll
    for (int t = 0; t < 4; ++t) {
      bf16x8 vf0 = *(const bf16x8*)&Vt[(size_t)(t*16 + lr) * SEQ + kvbase + lg * 8];
      bf16x8 vf1 = *(const bf16x8*)&Vt[(size_t)(t*16 + lr) * SEQ + kvbase + 32 + lg * 8];
      oacc[t] = __builtin_amdgcn_mfma_f32_16x16x32_bf16(pf0, vf0, oacc[t], 0, 0, 0);
      oacc[t] = __builtin_amdgcn_mfma_f32_16x16x32_bf16(pf1, vf1, oacc[t], 0, 0, 0);
    }
  }
  // ---- epilogue: O / l -> ows [b,s,h*64+d] ----
  #pragma unroll
  for (int t = 0; t < 4; ++t) {
    #pragma unroll
    for (int r = 0; r < 4; ++r) {
      int q = qbase + lg*4 + r;
      float v = oacc[t][r] / lrow[r];
      ows[((size_t)(b * SEQ + q)) * D_MODEL + h * DK + t*16 + lr] = f2bf(v);
    }
  }
}

// ---------------- launch ----------------
extern "C" void kernel_launch(void* const* d_in, const int* in_sizes, int n_in,
                              void* d_out, int out_size, void* d_ws, size_t ws_size,
                              hipStream_t stream) {
  const float* x  = (const float*)d_in[0];
  const float* wq = (const float*)d_in[1];
  const float* bq = (const float*)d_in[2];
  const float* wk = (const float*)d_in[3];
  const float* bk = (const float*)d_in[4];
  const float* wv = (const float*)d_in[5];
  const float* bv = (const float*)d_in[6];
  const float* wo = (const float*)d_in[7];
  const float* bo = (const float*)d_in[8];
  float* out = (float*)d_out;

  // workspace layout (bytes). Requires ws_size >= 48 MiB.
  char* ws = (char*)d_ws;
  u16* qws  = (u16*)(ws + (size_t) 0 * (1 << 20));  // [b,h,s,dk]  8 MiB
  u16* kws  = (u16*)(ws + (size_t) 8 * (1 << 20));  // [b,h,s,dk]  8 MiB
  u16* vtws = (u16*)(ws + (size_t)16 * (1 << 20));  // [b,h,dk,s]  8 MiB
  u16* ows  = (u16*)(ws + (size_t)24 * (1 << 20));  // [b,s,d]     8 MiB
  u16* xbf  = (u16*)(ws + (size_t)32 * (1 << 20));  // [m,1024]    8 MiB
  u16* wbf  = (u16*)(ws + (size_t)40 * (1 << 20));  // wq|wk|wv|wo 8 MiB

  // fp32 -> bf16
  cvt_kernel<<<2048, 256, 0, stream>>>(x, xbf, M_TOT * D_MODEL / 8);
  cvt_kernel<<<512, 256, 0, stream>>>(wq, wbf + (size_t)0 * 1024 * 1024, 1024 * 1024 / 8);
  cvt_kernel<<<512, 256, 0, stream>>>(wk, wbf + (size_t)1 * 1024 * 1024, 1024 * 1024 / 8);
  cvt_kernel<<<512, 256, 0, stream>>>(wv, wbf + (size_t)2 * 1024 * 1024, 1024 * 1024 / 8);
  cvt_kernel<<<512, 256, 0, stream>>>(wo, wbf + (size_t)3 * 1024 * 1024, 1024 * 1024 / 8);

  // Q/K/V projections (z selects output)
  qkv_gemm<<<dim3(1024 / BN, M_TOT / BM, 3), 256, 0, stream>>>(
      xbf, wbf, bq, bk, bv, qws, kws, vtws);

  // causal flash attention
  attn_kernel<<<dim3(SEQ / 64, NHEAD, BATCH), 256, 0, stream>>>(qws, kws, vtws, ows);

  // output projection (fp32 out)
  out_gemm<<<dim3(1024 / BN, M_TOT / BM), 256, 0, stream>>>(
      ows, wbf + (size_t)3 * 1024 * 1024, bo, out);
}

// Round 2
// 156.168 us; speedup vs baseline: 2.0771x; 2.0771x over previous
//
#include <hip/hip_runtime.h>

// Problem constants
#define D_MODEL 1024
#define NHEAD   16
#define DK      64
#define BATCH   2
#define SEQ     2048
#define M_TOT   (BATCH*SEQ)   // 4096

typedef unsigned short u16;
typedef unsigned int   u32;
typedef __attribute__((ext_vector_type(8))) __bf16 bf16x8;
typedef __attribute__((ext_vector_type(8))) u16   u16x8;
typedef __attribute__((ext_vector_type(4))) u16   u16x4;
typedef __attribute__((ext_vector_type(4))) float f32x4;

typedef const __attribute__((address_space(1))) u32* gas_ptr;
typedef __attribute__((address_space(3))) u32*       las_ptr;

__device__ __forceinline__ void gload16(const u16* g, u16* l) {
  __builtin_amdgcn_global_load_lds((gas_ptr)g, (las_ptr)l, 16, 0, 0);
}

__device__ __forceinline__ u16 f2bf(float f) {
  union { float f; unsigned u; } v; v.f = f;
  return (u16)((v.u + 0x7fffu + ((v.u >> 16) & 1u)) >> 16);
}

// ---------------- fp32 -> bf16 convert, 8 elems/thread ----------------
__global__ void cvt_kernel(const float* __restrict__ src, u16* __restrict__ dst, int n8) {
  int i = blockIdx.x * blockDim.x + threadIdx.x;
  if (i >= n8) return;
  const float4* s = (const float4*)src + (size_t)i * 2;
  float4 a = s[0], b = s[1];
  u16x8 o;
  o[0]=f2bf(a.x); o[1]=f2bf(a.y); o[2]=f2bf(a.z); o[3]=f2bf(a.w);
  o[4]=f2bf(b.x); o[5]=f2bf(b.y); o[6]=f2bf(b.z); o[7]=f2bf(b.w);
  *((u16x8*)dst + i) = o;
}

// ---------------- shared GEMM mainloop (m97 pattern) ----------------
// C[m,n] = sum_k A[m,k]*B[n,k]; bf16, K=1024 contiguous.
// 128x128 tile, BK=32, 256 thr = 4 waves (2x2), wave = 64x64 = 4x4 frags.
// global_load_lds 16B staging, double-buffered, 1 barrier / K-step.
#define BM 128
#define BN 128
#define BK 32

__device__ __forceinline__ void gemm_mainloop(
    const u16* __restrict__ A, const u16* __restrict__ Bm,
    int mbase, int nbase, u16* la, u16* lb, f32x4 acc[4][4])
{
  const int tid  = threadIdx.x;
  const int lane = tid & 63;
  const int wid  = tid >> 6;
  const int wr   = (wid >> 1) * 64, wc = (wid & 1) * 64;
  const int lr   = lane & 15, lg = lane >> 4;
  const int srow = tid >> 2;          // 0..63 (+64 second op)
  const int skc  = (tid & 3) * 8;     // k-chunk elem offset

  // prologue: stage k0=0 into buf 0
  {
    const size_t a0 = (size_t)(mbase + srow) * 1024 + skc;
    const size_t b0 = (size_t)(nbase + srow) * 1024 + skc;
    gload16(&A[a0],             &la[srow*32 + skc]);
    gload16(&A[a0 + 64*1024],   &la[(srow+64)*32 + skc]);
    gload16(&Bm[b0],            &lb[srow*32 + skc]);
    gload16(&Bm[b0 + 64*1024],  &lb[(srow+64)*32 + skc]);
  }
  __syncthreads();
  int cur = 0;
  for (int k0 = 0; k0 < 1024; k0 += BK) {
    if (k0 + BK < 1024) {
      const int nb = cur ^ 1;
      const size_t a0 = (size_t)(mbase + srow) * 1024 + k0 + BK + skc;
      const size_t b0 = (size_t)(nbase + srow) * 1024 + k0 + BK + skc;
      gload16(&A[a0],            &la[nb*4096 + srow*32 + skc]);
      gload16(&A[a0 + 64*1024],  &la[nb*4096 + (srow+64)*32 + skc]);
      gload16(&Bm[b0],           &lb[nb*4096 + srow*32 + skc]);
      gload16(&Bm[b0 + 64*1024], &lb[nb*4096 + (srow+64)*32 + skc]);
    }
    bf16x8 af[4], bfr[4];
    #pragma unroll
    for (int i = 0; i < 4; ++i)
      af[i] = *(const bf16x8*)&la[cur*4096 + (wr + i*16 + lr)*32 + lg*8];
    #pragma unroll
    for (int j = 0; j < 4; ++j)
      bfr[j] = *(const bf16x8*)&lb[cur*4096 + (wc + j*16 + lr)*32 + lg*8];
    #pragma unroll
    for (int i = 0; i < 4; ++i)
      #pragma unroll
      for (int j = 0; j < 4; ++j)
        acc[i][j] = __builtin_amdgcn_mfma_f32_16x16x32_bf16(af[i], bfr[j], acc[i][j], 0, 0, 0);
    __syncthreads();
    cur ^= 1;
  }
}

// Q scale: 1/sqrt(64) * log2(e)  (attention works in exp2 domain)
#define QSCALE 0.18033688011112042f

// ---------------- fused QKV projection ----------------
__global__ __launch_bounds__(256) void qkv_gemm(
    const u16* __restrict__ xbf, const u16* __restrict__ wbf,
    const float* __restrict__ bq, const float* __restrict__ bk, const float* __restrict__ bv,
    u16* __restrict__ qws, u16* __restrict__ kws, u16* __restrict__ vtws)
{
  __shared__ u16 la[2 * 128 * 32];
  __shared__ u16 lb[2 * 128 * 32];
  const int z     = blockIdx.z;
  const int nbase = blockIdx.x * BN;
  const int mbase = blockIdx.y * BM;
  const u16*  Bw   = wbf + (size_t)z * 1024 * 1024;
  const float* bias = (z == 0) ? bq : (z == 1) ? bk : bv;
  f32x4 acc[4][4];
  #pragma unroll
  for (int i = 0; i < 4; ++i)
    #pragma unroll
    for (int j = 0; j < 4; ++j)
      acc[i][j] = (f32x4){0.f, 0.f, 0.f, 0.f};
  gemm_mainloop(xbf, Bw, mbase, nbase, la, lb, acc);

  const int lane = threadIdx.x & 63;
  const int wid  = threadIdx.x >> 6;
  const int wr   = (wid >> 1) * 64, wc = (wid & 1) * 64;
  const int lr   = lane & 15, lg = lane >> 4;
  #pragma unroll
  for (int i = 0; i < 4; ++i) {
    #pragma unroll
    for (int j = 0; j < 4; ++j) {
      int gn = nbase + wc + j*16 + lr;
      float bs = bias[gn];
      int h = gn >> 6, d = gn & 63;
      #pragma unroll
      for (int r = 0; r < 4; ++r) {
        int gm = mbase + wr + i*16 + lg*4 + r;
        int bb = gm >> 11, s = gm & 2047;
        float v = acc[i][j][r] + bs;
        if (z == 0)      qws [(((size_t)(bb*NHEAD + h)) * SEQ + s) * DK + d] = f2bf(v * QSCALE);
        else if (z == 1) kws [(((size_t)(bb*NHEAD + h)) * SEQ + s) * DK + d] = f2bf(v);
        else             vtws[(((size_t)(bb*NHEAD + h)) * DK  + d) * SEQ + s] = f2bf(v);
      }
    }
  }
}

// ---------------- output projection ----------------
__global__ __launch_bounds__(256) void out_gemm(
    const u16* __restrict__ ows, const u16* __restrict__ wobf,
    const float* __restrict__ bo, float* __restrict__ out)
{
  __shared__ u16 la[2 * 128 * 32];
  __shared__ u16 lb[2 * 128 * 32];
  const int nbase = blockIdx.x * BN;
  const int mbase = blockIdx.y * BM;
  f32x4 acc[4][4];
  #pragma unroll
  for (int i = 0; i < 4; ++i)
    #pragma unroll
    for (int j = 0; j < 4; ++j)
      acc[i][j] = (f32x4){0.f, 0.f, 0.f, 0.f};
  gemm_mainloop(ows, wobf, mbase, nbase, la, lb, acc);

  const int lane = threadIdx.x & 63;
  const int wid  = threadIdx.x >> 6;
  const int wr   = (wid >> 1) * 64, wc = (wid & 1) * 64;
  const int lr   = lane & 15, lg = lane >> 4;
  #pragma unroll
  for (int i = 0; i < 4; ++i) {
    #pragma unroll
    for (int j = 0; j < 4; ++j) {
      int gn = nbase + wc + j*16 + lr;
      float bs = bo[gn];
      #pragma unroll
      for (int r = 0; r < 4; ++r) {
        int gm = mbase + wr + i*16 + lg*4 + r;
        out[(size_t)gm * 1024 + gn] = acc[i][j][r] + bs;
      }
    }
  }
}

// ---------------- flash-style causal attention (swapped QK^T) ----------------
// grid (32, 16, 2). 4 waves/block; block owns a 64-row q-tile, wave wid owns
// 16 q-rows (q = qtile*64 + wid*16 + lr). KV tiles of 64, LDS-staged (XOR-
// swizzled via pre-swizzled global source), double-buffered 2-phase prefetch.
// S^T = mfma(K, Q): lane holds 16 kv-values of ONE q-row -> in-lane softmax.
__global__ __launch_bounds__(256) void attn_kernel(
    const u16* __restrict__ qws, const u16* __restrict__ kws,
    const u16* __restrict__ vtws, u16* __restrict__ ows)
{
  __shared__ u16 kbuf[2 * 64 * 64];   // [buf][kv][k-chunks swizzled]  16 KB
  __shared__ u16 vbuf[2 * 64 * 64];   // [buf][d][kv-chunks swizzled]  16 KB
  __shared__ u16 pbuf[4 * 16 * 64];   // per-wave P^T [q][kv swizzled]  8 KB
  const int qt = 31 - blockIdx.x;
  const int h  = blockIdx.y, b = blockIdx.z;
  const int bh = b * NHEAD + h;
  const int tid = threadIdx.x, wid = tid >> 6, lane = tid & 63;
  const int lr = lane & 15, lg = lane >> 4;
  const u16* Q  = qws  + (size_t)bh * SEQ * DK;
  const u16* K  = kws  + (size_t)bh * SEQ * DK;
  const u16* Vt = vtws + (size_t)bh * DK * SEQ;
  const int qbase  = qt * 64 + wid * 16;
  const int q_glob = qbase + lr;

  // staging: thread covers rows sr and sr+32, chunk (tid&7); swizzled source
  const int sr  = tid >> 3;           // 0..31
  const int sc  = tid & 7;            // chunk index
  const int sc8 = sc * 8;             // dest elem offset
  const int c0s = (sc ^ (sr & 7)) * 8;        // swizzled src chunk, row sr
  const int c1s = (sc ^ ((sr + 32) & 7)) * 8; // swizzled src chunk, row sr+32

  // Q fragments (B operand): lane holds Q[q_glob][lg*8 + i] (+32 second half)
  bf16x8 qf0 = *(const bf16x8*)&Q[(size_t)q_glob * DK + lg * 8];
  bf16x8 qf1 = *(const bf16x8*)&Q[(size_t)q_glob * DK + 32 + lg * 8];

  f32x4 oacc[4];
  #pragma unroll
  for (int t = 0; t < 4; ++t) oacc[t] = (f32x4){0.f, 0.f, 0.f, 0.f};
  float m_run = -1e30f, l_run = 0.f;

  // prologue stage of tile 0
  {
    gload16(&K[(size_t)sr * DK + c0s],          &kbuf[sr * 64 + sc8]);
    gload16(&K[(size_t)(sr + 32) * DK + c1s],   &kbuf[(sr + 32) * 64 + sc8]);
    gload16(&Vt[(size_t)sr * SEQ + c0s],        &vbuf[sr * 64 + sc8]);
    gload16(&Vt[(size_t)(sr + 32) * SEQ + c1s], &vbuf[(sr + 32) * 64 + sc8]);
  }
  __syncthreads();

  int cur = 0;
  #define CH(m) ((((m)*4 + lg) ^ (lr & 7)) * 8)
  for (int kvt = 0; kvt <= qt; ++kvt) {
    // prefetch next KV tile into other buffer
    if (kvt < qt) {
      const int nb = (cur ^ 1) * 4096;
      const int kb = (kvt + 1) * 64;
      gload16(&K[(size_t)(kb + sr) * DK + c0s],        &kbuf[nb + sr * 64 + sc8]);
      gload16(&K[(size_t)(kb + sr + 32) * DK + c1s],   &kbuf[nb + (sr + 32) * 64 + sc8]);
      gload16(&Vt[(size_t)sr * SEQ + kb + c0s],        &vbuf[nb + sr * 64 + sc8]);
      gload16(&Vt[(size_t)(sr + 32) * SEQ + kb + c1s], &vbuf[nb + (sr + 32) * 64 + sc8]);
    }
    const int diag = (kvt == qt);
    const int nsub = diag ? (wid + 1) : 4;   // wave-uniform
    const int cb = cur * 4096;

    // ---- S^T = K Q^T : sacc[t][r] is S[kv = kvt*64 + t*16 + lg*4 + r][q_glob]
    f32x4 sacc[4];
    #pragma unroll
    for (int t = 0; t < 4; ++t) {
      if (t >= nsub) continue;
      bf16x8 kf0 = *(const bf16x8*)&kbuf[cb + (t*16 + lr) * 64 + CH(0)];
      bf16x8 kf1 = *(const bf16x8*)&kbuf[cb + (t*16 + lr) * 64 + CH(1)];
      f32x4 s0 = (f32x4){0.f, 0.f, 0.f, 0.f};
      s0 = __builtin_amdgcn_mfma_f32_16x16x32_bf16(kf0, qf0, s0, 0, 0, 0);
      s0 = __builtin_amdgcn_mfma_f32_16x16x32_bf16(kf1, qf1, s0, 0, 0, 0);
      sacc[t] = s0;
    }
    // ---- causal mask: only subtile t==wid of the diagonal tile straddles
    if (diag) {
      const int t = wid;
      #pragma unroll
      for (int r = 0; r < 4; ++r)
        if (lg * 4 + r > lr) sacc[t][r] = -1e30f;
    }
    // ---- online softmax, in-lane (lane owns one q-row's kv-slice)
    float mx = -1e30f;
    #pragma unroll
    for (int t = 0; t < 4; ++t) {
      if (t >= nsub) continue;
      mx = fmaxf(fmaxf(fmaxf(sacc[t][0], sacc[t][1]), fmaxf(sacc[t][2], sacc[t][3])), mx);
    }
    mx = fmaxf(mx, __shfl_xor(mx, 16));
    mx = fmaxf(mx, __shfl_xor(mx, 32));
    const float mnew  = fmaxf(m_run, mx);
    const float alpha = __builtin_amdgcn_exp2f(m_run - mnew);
    m_run = mnew;
    float ps = 0.f;
    #pragma unroll
    for (int t = 0; t < 4; ++t) {
      if (t >= nsub) continue;
      #pragma unroll
      for (int r = 0; r < 4; ++r) {
        float p = __builtin_amdgcn_exp2f(sacc[t][r] - mnew);
        sacc[t][r] = p;
        ps += p;
      }
    }
    ps += __shfl_xor(ps, 16);
    ps += __shfl_xor(ps, 32);
    l_run = l_run * alpha + ps;
    #pragma unroll
    for (int t = 0; t < 4; ++t)
      #pragma unroll
      for (int r = 0; r < 4; ++r) oacc[t][r] *= alpha;

    // ---- P^T -> bf16 -> LDS (b64 packed, swizzled); zeros for skipped subtiles
    #pragma unroll
    for (int t = 0; t < 4; ++t) {
      u16x4 pk;
      if (t < nsub) {
        pk[0] = f2bf(sacc[t][0]); pk[1] = f2bf(sacc[t][1]);
        pk[2] = f2bf(sacc[t][2]); pk[3] = f2bf(sacc[t][3]);
      } else {
        pk[0] = 0; pk[1] = 0; pk[2] = 0; pk[3] = 0;
      }
      const int pc = (((t*2 + (lg >> 1)) ^ (lr & 7)) * 8) + (lg & 1) * 4;
      *(u16x4*)&pbuf[wid * 1024 + lr * 64 + pc] = pk;
    }
    asm volatile("s_waitcnt lgkmcnt(0)" ::: "memory");
    __builtin_amdgcn_sched_barrier(0);
    bf16x8 pf0 = *(const bf16x8*)&pbuf[wid * 1024 + lr * 64 + CH(0)];
    bf16x8 pf1 = *(const bf16x8*)&pbuf[wid * 1024 + lr * 64 + CH(1)];

    // ---- O^T += V P : oacc[td][r] is O[q_glob][d = td*16 + lg*4 + r]
    #pragma unroll
    for (int td = 0; td < 4; ++td) {
      bf16x8 vf0 = *(const bf16x8*)&vbuf[cb + (td*16 + lr) * 64 + CH(0)];
      bf16x8 vf1 = *(const bf16x8*)&vbuf[cb + (td*16 + lr) * 64 + CH(1)];
      oacc[td] = __builtin_amdgcn_mfma_f32_16x16x32_bf16(vf0, pf0, oacc[td], 0, 0, 0);
      oacc[td] = __builtin_amdgcn_mfma_f32_16x16x32_bf16(vf1, pf1, oacc[td], 0, 0, 0);
    }
    __syncthreads();
    cur ^= 1;
  }
  #undef CH

  // ---- epilogue: O / l -> ows [b, q, h*64 + d]  (b64 packed stores)
  const float inv = 1.0f / l_run;
  #pragma unroll
  for (int td = 0; td < 4; ++td) {
    u16x4 ok;
    #pragma unroll
    for (int r = 0; r < 4; ++r) ok[r] = f2bf(oacc[td][r] * inv);
    *(u16x4*)&ows[((size_t)(b * SEQ + q_glob)) * D_MODEL + h * DK + td*16 + lg*4] = ok;
  }
}

// ---------------- launch ----------------
extern "C" void kernel_launch(void* const* d_in, const int* in_sizes, int n_in,
                              void* d_out, int out_size, void* d_ws, size_t ws_size,
                              hipStream_t stream) {
  const float* x  = (const float*)d_in[0];
  const float* wq = (const float*)d_in[1];
  const float* bq = (const float*)d_in[2];
  const float* wk = (const float*)d_in[3];
  const float* bk = (const float*)d_in[4];
  const float* wv = (const float*)d_in[5];
  const float* bv = (const float*)d_in[6];
  const float* wo = (const float*)d_in[7];
  const float* bo = (const float*)d_in[8];
  float* out = (float*)d_out;

  char* ws = (char*)d_ws;
  u16* qws  = (u16*)(ws + (size_t) 0 * (1 << 20));  // [b,h,s,dk]  8 MiB
  u16* kws  = (u16*)(ws + (size_t) 8 * (1 << 20));  // [b,h,s,dk]  8 MiB
  u16* vtws = (u16*)(ws + (size_t)16 * (1 << 20));  // [b,h,dk,s]  8 MiB
  u16* ows  = (u16*)(ws + (size_t)24 * (1 << 20));  // [b,s,d]     8 MiB
  u16* xbf  = (u16*)(ws + (size_t)32 * (1 << 20));  // [m,1024]    8 MiB
  u16* wbf  = (u16*)(ws + (size_t)40 * (1 << 20));  // wq|wk|wv|wo 8 MiB

  cvt_kernel<<<2048, 256, 0, stream>>>(x, xbf, M_TOT * D_MODEL / 8);
  cvt_kernel<<<512, 256, 0, stream>>>(wq, wbf + (size_t)0 * 1024 * 1024, 1024 * 1024 / 8);
  cvt_kernel<<<512, 256, 0, stream>>>(wk, wbf + (size_t)1 * 1024 * 1024, 1024 * 1024 / 8);
  cvt_kernel<<<512, 256, 0, stream>>>(wv, wbf + (size_t)2 * 1024 * 1024, 1024 * 1024 / 8);
  cvt_kernel<<<512, 256, 0, stream>>>(wo, wbf + (size_t)3 * 1024 * 1024, 1024 * 1024 / 8);

  qkv_gemm<<<dim3(1024 / BN, M_TOT / BM, 3), 256, 0, stream>>>(
      xbf, wbf, bq, bk, bv, qws, kws, vtws);

  attn_kernel<<<dim3(SEQ / 64, NHEAD, BATCH), 256, 0, stream>>>(qws, kws, vtws, ows);

  out_gemm<<<dim3(1024 / BN, M_TOT / BM), 256, 0, stream>>>(
      ows, wbf + (size_t)3 * 1024 * 1024, bo, out);
}